// Round 13
// baseline (50.809 us; speedup 1.0000x reference)
//
#include <hip/hip_runtime.h>
#include <cstdint>
#include <cstddef>

typedef int v4i  __attribute__((ext_vector_type(4)));
typedef int v16i __attribute__((ext_vector_type(16)));

#define QMIN_F (-128.0f)
#define QMAX_F (127.0f)
#define SMALL_THR 6.1e-05f

#define WAITVM(n) asm volatile("s_waitcnt vmcnt(" #n ")" ::: "memory")
#define SCHEDBAR __builtin_amdgcn_sched_barrier(0)

// ---------------------------------------------------------------------------
// Kernel 1: per-row dynamic quantization + fused weight pack (at BW roofline).
// ---------------------------------------------------------------------------
__global__ __launch_bounds__(256) void quant_rows_kernel(
    const float* __restrict__ x, signed char* __restrict__ q,
    float* __restrict__ scales, int* __restrict__ zps, int* __restrict__ sums,
    const int* __restrict__ w32, int* __restrict__ w8pk, int n4, int K) {
  const int gidx = blockIdx.x * 256 + threadIdx.x;
  if (gidx < n4) {
    v4i pv = *(const v4i*)(w32 + gidx * 4);
    w8pk[gidx] = (pv.x & 255) | ((pv.y & 255) << 8) | ((pv.z & 255) << 16) |
                 (pv.w << 24);
  }

  const int wave = threadIdx.x >> 6;
  const int lane = threadIdx.x & 63;
  const int row  = blockIdx.x * 4 + wave;
  const float* xr = x + (size_t)row * K;

  float4 v[4];
  float vmin = 0.0f, vmax = 0.0f, vsum = 0.0f;
#pragma unroll
  for (int j = 0; j < 4; ++j) {
    v[j] = *(const float4*)(xr + j * 256 + lane * 4);
    vmin = fminf(vmin, fminf(fminf(v[j].x, v[j].y), fminf(v[j].z, v[j].w)));
    vmax = fmaxf(vmax, fmaxf(fmaxf(v[j].x, v[j].y), fmaxf(v[j].z, v[j].w)));
    vsum += (v[j].x + v[j].y) + (v[j].z + v[j].w);
  }
#pragma unroll
  for (int off = 32; off >= 1; off >>= 1) {
    vmin = fminf(vmin, __shfl_xor(vmin, off));
    vmax = fmaxf(vmax, __shfl_xor(vmax, off));
    vsum += __shfl_xor(vsum, off);
  }

  float scale = (vmax - vmin) / (QMAX_F - QMIN_F);
  float isinf_f = isinf(1.0f / scale) ? 1.0f : 0.0f;
  if (scale == isinf_f) scale = 0.1f;
  float rmin = vmin, rmax = vmax;
  if (scale < SMALL_THR) {
    float amp = SMALL_THR / scale;
    scale = SMALL_THR;
    rmax *= amp;
    rmin *= amp;
  }
  float rdmin = rmin / scale, rdmax = rmax / scale;
  float err_min = 128.0f + fabsf(rdmin);
  float err_max = 127.0f + fabsf(rdmax);
  float zp0 = (err_min < err_max) ? (QMIN_F - rdmin) : (QMAX_F - rdmax);
  int zp = (int)rintf(zp0);
  if (zp0 < QMIN_F) zp = -128;
  if (zp0 > QMAX_F) zp = 127;
  float inv = 1.0f / scale;

  if (lane == 0) {
    scales[row] = scale;
    zps[row]    = zp;
    sums[row]   = (int)rintf(vsum * inv);
  }

  const float zpf = (float)zp;
  int* qi = (int*)(q + (size_t)row * K);
#pragma unroll
  for (int j = 0; j < 4; ++j) {
    float t0 = fminf(fmaxf(rintf(v[j].x * inv) + zpf, QMIN_F), QMAX_F);
    float t1 = fminf(fmaxf(rintf(v[j].y * inv) + zpf, QMIN_F), QMAX_F);
    float t2 = fminf(fmaxf(rintf(v[j].z * inv) + zpf, QMIN_F), QMAX_F);
    float t3 = fminf(fmaxf(rintf(v[j].w * inv) + zpf, QMIN_F), QMAX_F);
    int pack = ((int)t0 & 255) | (((int)t1 & 255) << 8) |
               (((int)t2 & 255) << 16) | ((int)t3 << 24);
    qi[j * 64 + lane] = pack;
  }
}

// ---------------------------------------------------------------------------
// Kernel 2: int8 GEMM + fused dequant — R12 structure with mfma_i32_32x32x32
// (4404 TOPS ceiling vs 16x16x64's 3944; 4x fewer MFMA instrs, same bytes).
// BM=256, BN=128, BK=64, 512 thr, 8 waves (4M x 2N, wave-out 64x64 = 2x2
// MFMAs of 32x32 x 2 K-steps; acc 2x2xv16i = 64 VGPR). Stage lead-2,
// tail-aware counted WAITVM(3); phase interleave with sched_barrier +
// setprio; swizzle slot^((row>>1)&3) both sides; plain stores; XCD chunk.
// A/B frag layout (assumed K-doubling analog, C/D is HW-verified):
// row=lane&31, 16 consecutive K bytes at slot kstep*2+(lane>>5).
// ---------------------------------------------------------------------------
__device__ __forceinline__ void gload_lds16(const void* g, void* l) {
  __builtin_amdgcn_global_load_lds(
      (const __attribute__((address_space(1))) void*)g,
      (__attribute__((address_space(3))) void*)l, 16, 0, 0);
}

#define BUFA_SZ 16384   // 256 rows x 64 B
#define BUFB_SZ 8192    // 128 rows x 64 B

// 3 gloads per thread: A 1024 chunks (2/thr), B 512 chunks (1/thr).
__device__ __forceinline__ void stage_tile(
    const signed char* __restrict__ q, const signed char* __restrict__ w,
    char* buf, int rowA0, int rowB0, int k0, int K, int tid) {
#pragma unroll
  for (int i = 0; i < 2; ++i) {
    int c  = (i << 9) + tid;
    int r  = c >> 2;
    int sl = (c & 3) ^ ((r >> 1) & 3);
    gload_lds16(q + (size_t)(rowA0 + r) * K + k0 + (sl << 4), buf + (c << 4));
  }
  {
    int c  = tid;
    int r  = c >> 2;
    int sl = (c & 3) ^ ((r >> 1) & 3);
    gload_lds16(w + (size_t)(rowB0 + r) * K + k0 + (sl << 4),
                buf + BUFA_SZ + (c << 4));
  }
}

__device__ __forceinline__ v4i lds_frag(const char* base, int row, int slot) {
  return *(const v4i*)(base + (row << 6) + ((slot ^ ((row >> 1) & 3)) << 4));
}

__global__ __launch_bounds__(512, 4) void gemm_dequant_kernel(
    const signed char* __restrict__ q, const signed char* __restrict__ w,
    const float* __restrict__ scales, const int* __restrict__ zps,
    const int* __restrict__ sums, const float* __restrict__ bias,
    const float* __restrict__ w_scales, const int* __restrict__ w_zeros,
    const int* __restrict__ w_sums, float* __restrict__ out,
    int N, int K, int nblk) {
  __shared__ char sh[2][BUFA_SZ + BUFB_SZ];  // 48 KB
  const int tid  = threadIdx.x;
  const int lane = tid & 63;
  const int wave = tid >> 6;                 // 0..7
  const int wrbase = (wave >> 1) << 6;       // 4 M-quarters of 64 rows
  const int wcbase = (wave & 1) << 6;        // 2 N-halves of 64 cols
  const int lrow = lane & 31;                // 32x32 frag row/col
  const int khalf = lane >> 5;               // 16-byte K-half within K=32
  const int ntN = N >> 7;                    // 8
  // XCD chunk (nblk % 8 == 0): 64 lins/XCD -> A 2 MB + w 1 MB fit 4 MB L2.
  const int per = nblk >> 3;
  const int lin = ((int)blockIdx.x & 7) * per + ((int)blockIdx.x >> 3);
  const int rowA0 = (lin / ntN) << 8;        // BM=256
  const int rowB0 = (lin % ntN) << 7;        // BN=128

  v16i acc00, acc01, acc10, acc11;
#pragma unroll
  for (int i = 0; i < 16; ++i) {
    acc00[i] = 0; acc01[i] = 0; acc10[i] = 0; acc11[i] = 0;
  }

  const int NT = K >> 6;                     // 16
  stage_tile(q, w, sh[0], rowA0, rowB0, 0, K, tid);
  stage_tile(q, w, sh[1], rowA0, rowB0, 64, K, tid);

  for (int t = 0; t < NT; ++t) {
    // Tail-aware counted wait (R11 lesson): last tile must fully drain.
    if (t + 1 < NT) { WAITVM(3); } else { WAITVM(0); }
    __builtin_amdgcn_s_barrier();            // all waves' DMA for tile t done

    const char* bA = sh[t & 1];
    const char* bB = bA + BUFA_SZ;

    // ---- phase 0: read K-step-0 frags (slot = khalf) ----
    v4i a00 = lds_frag(bA, wrbase + 0  + lrow, khalf);
    v4i a01 = lds_frag(bA, wrbase + 32 + lrow, khalf);
    v4i b00 = lds_frag(bB, wcbase + 0  + lrow, khalf);
    v4i b01 = lds_frag(bB, wcbase + 32 + lrow, khalf);
    SCHEDBAR;
    // ---- phase 1: issue K-step-1 reads (slot = 2+khalf), MFMA K-step 0 ----
    v4i a10 = lds_frag(bA, wrbase + 0  + lrow, 2 + khalf);
    v4i a11 = lds_frag(bA, wrbase + 32 + lrow, 2 + khalf);
    v4i b10 = lds_frag(bB, wcbase + 0  + lrow, 2 + khalf);
    v4i b11 = lds_frag(bB, wcbase + 32 + lrow, 2 + khalf);
    __builtin_amdgcn_s_setprio(1);
    acc00 = __builtin_amdgcn_mfma_i32_32x32x32_i8(a00, b00, acc00, 0, 0, 0);
    acc01 = __builtin_amdgcn_mfma_i32_32x32x32_i8(a00, b01, acc01, 0, 0, 0);
    acc10 = __builtin_amdgcn_mfma_i32_32x32x32_i8(a01, b00, acc10, 0, 0, 0);
    acc11 = __builtin_amdgcn_mfma_i32_32x32x32_i8(a01, b01, acc11, 0, 0, 0);
    __builtin_amdgcn_s_setprio(0);
    SCHEDBAR;
    // ---- phase 2: MFMA K-step 1 ----
    __builtin_amdgcn_s_setprio(1);
    acc00 = __builtin_amdgcn_mfma_i32_32x32x32_i8(a10, b10, acc00, 0, 0, 0);
    acc01 = __builtin_amdgcn_mfma_i32_32x32x32_i8(a10, b11, acc01, 0, 0, 0);
    acc10 = __builtin_amdgcn_mfma_i32_32x32x32_i8(a11, b10, acc10, 0, 0, 0);
    acc11 = __builtin_amdgcn_mfma_i32_32x32x32_i8(a11, b11, acc11, 0, 0, 0);
    __builtin_amdgcn_s_setprio(0);
    SCHEDBAR;

    __builtin_amdgcn_s_barrier();            // all reads of buf[t&1] consumed
    if (t + 2 < NT)                          // refill just-freed buffer
      stage_tile(q, w, sh[t & 1], rowA0, rowB0, (t + 2) << 6, K, tid);
  }

  // Epilogue. 32x32 C/D layout (HW-verified): col = lane&31,
  // row = (reg&3) + 8*(reg>>2) + 4*(lane>>5).
  const int baseM = rowA0 + wrbase;
  const int baseN = rowB0 + wcbase;
  float cb[2], cwsc[2];
  int cwz[2], cws[2];
#pragma unroll
  for (int n = 0; n < 2; ++n) {
    int col = baseN + (n << 5) + lrow;
    cb[n]   = bias[col];
    cwsc[n] = w_scales[col];
    cwz[n]  = w_zeros[col];
    cws[n]  = w_sums[col];
  }
#pragma unroll
  for (int mi = 0; mi < 2; ++mi) {
#pragma unroll
    for (int g = 0; g < 4; ++g) {
      const int r0 = baseM + (mi << 5) + (g << 3) + (khalf << 2);
      float sc[4];
      int zp4[4], sm4[4];
#pragma unroll
      for (int j = 0; j < 4; ++j) {
        sc[j]  = scales[r0 + j];
        zp4[j] = zps[r0 + j];
        sm4[j] = sums[r0 + j];
      }
#pragma unroll
      for (int n = 0; n < 2; ++n) {
        const int col = baseN + (n << 5) + lrow;
#pragma unroll
        for (int j = 0; j < 4; ++j) {
          int d;
          if (mi == 0 && n == 0) d = acc00[(g << 2) + j];
          else if (mi == 0)      d = acc01[(g << 2) + j];
          else if (n == 0)       d = acc10[(g << 2) + j];
          else                   d = acc11[(g << 2) + j];
          int temp = zp4[j] * cws[n] + sm4[j] * cwz[n];
          out[(size_t)(r0 + j) * N + col] =
              cb[n] + (float)(d - temp) * (sc[j] * cwsc[n]);
        }
      }
    }
  }
}

extern "C" void kernel_launch(void* const* d_in, const int* in_sizes, int n_in,
                              void* d_out, int out_size, void* d_ws, size_t ws_size,
                              hipStream_t stream) {
  const float* inp      = (const float*)d_in[0];
  const int*   qw32     = (const int*)d_in[1];   // int8 in ref -> int32 on device
  const float* bias     = (const float*)d_in[2];
  const float* w_scales = (const float*)d_in[3];
  const int*   w_zeros  = (const int*)d_in[4];
  const int*   w_sums   = (const int*)d_in[5];

  const int N = in_sizes[2];      // 1024
  const int K = in_sizes[1] / N;  // 1024
  const int M = in_sizes[0] / K;  // 16384

  float*       scales = (float*)d_ws;
  int*         zps    = (int*)((char*)d_ws + (size_t)M * 4);
  int*         sums   = (int*)((char*)d_ws + (size_t)M * 8);
  signed char* q      = (signed char*)((char*)d_ws + (size_t)M * 12);
  signed char* w8     = (signed char*)((char*)d_ws + (size_t)M * 12 + (size_t)M * K);

  const int n4 = (N * K) / 4;
  const int nblk = (M / 256) * (N / 128);    // 512 blocks = 2/CU
  quant_rows_kernel<<<M / 4, 256, 0, stream>>>(inp, q, scales, zps, sums,
                                               qw32, (int*)w8, n4, K);
  gemm_dequant_kernel<<<nblk, 512, 0, stream>>>(
      q, w8, scales, zps, sums, bias, w_scales, w_zeros, w_sums,
      (float*)d_out, N, K, nblk);
}

// Round 14
// 46.161 us; speedup vs baseline: 1.1007x; 1.1007x over previous
//
#include <hip/hip_runtime.h>
#include <cstdint>
#include <cstddef>

typedef int v4i __attribute__((ext_vector_type(4)));

#define QMIN_F (-128.0f)
#define QMAX_F (127.0f)
#define SMALL_THR 6.1e-05f

#define WAITVM(n) asm volatile("s_waitcnt vmcnt(" #n ")" ::: "memory")
#define SCHEDBAR __builtin_amdgcn_sched_barrier(0)

// ---------------------------------------------------------------------------
// Kernel 1: per-row dynamic quantization + fused weight pack (at BW roofline).
// ---------------------------------------------------------------------------
__global__ __launch_bounds__(256) void quant_rows_kernel(
    const float* __restrict__ x, signed char* __restrict__ q,
    float* __restrict__ scales, int* __restrict__ zps, int* __restrict__ sums,
    const int* __restrict__ w32, int* __restrict__ w8pk, int n4, int K) {
  const int gidx = blockIdx.x * 256 + threadIdx.x;
  if (gidx < n4) {
    v4i pv = *(const v4i*)(w32 + gidx * 4);
    w8pk[gidx] = (pv.x & 255) | ((pv.y & 255) << 8) | ((pv.z & 255) << 16) |
                 (pv.w << 24);
  }

  const int wave = threadIdx.x >> 6;
  const int lane = threadIdx.x & 63;
  const int row  = blockIdx.x * 4 + wave;
  const float* xr = x + (size_t)row * K;

  float4 v[4];
  float vmin = 0.0f, vmax = 0.0f, vsum = 0.0f;
#pragma unroll
  for (int j = 0; j < 4; ++j) {
    v[j] = *(const float4*)(xr + j * 256 + lane * 4);
    vmin = fminf(vmin, fminf(fminf(v[j].x, v[j].y), fminf(v[j].z, v[j].w)));
    vmax = fmaxf(vmax, fmaxf(fmaxf(v[j].x, v[j].y), fmaxf(v[j].z, v[j].w)));
    vsum += (v[j].x + v[j].y) + (v[j].z + v[j].w);
  }
#pragma unroll
  for (int off = 32; off >= 1; off >>= 1) {
    vmin = fminf(vmin, __shfl_xor(vmin, off));
    vmax = fmaxf(vmax, __shfl_xor(vmax, off));
    vsum += __shfl_xor(vsum, off);
  }

  float scale = (vmax - vmin) / (QMAX_F - QMIN_F);
  float isinf_f = isinf(1.0f / scale) ? 1.0f : 0.0f;
  if (scale == isinf_f) scale = 0.1f;
  float rmin = vmin, rmax = vmax;
  if (scale < SMALL_THR) {
    float amp = SMALL_THR / scale;
    scale = SMALL_THR;
    rmax *= amp;
    rmin *= amp;
  }
  float rdmin = rmin / scale, rdmax = rmax / scale;
  float err_min = 128.0f + fabsf(rdmin);
  float err_max = 127.0f + fabsf(rdmax);
  float zp0 = (err_min < err_max) ? (QMIN_F - rdmin) : (QMAX_F - rdmax);
  int zp = (int)rintf(zp0);
  if (zp0 < QMIN_F) zp = -128;
  if (zp0 > QMAX_F) zp = 127;
  float inv = 1.0f / scale;

  if (lane == 0) {
    scales[row] = scale;
    zps[row]    = zp;
    sums[row]   = (int)rintf(vsum * inv);
  }

  const float zpf = (float)zp;
  int* qi = (int*)(q + (size_t)row * K);
#pragma unroll
  for (int j = 0; j < 4; ++j) {
    float t0 = fminf(fmaxf(rintf(v[j].x * inv) + zpf, QMIN_F), QMAX_F);
    float t1 = fminf(fmaxf(rintf(v[j].y * inv) + zpf, QMIN_F), QMAX_F);
    float t2 = fminf(fmaxf(rintf(v[j].z * inv) + zpf, QMIN_F), QMAX_F);
    float t3 = fminf(fmaxf(rintf(v[j].w * inv) + zpf, QMIN_F), QMAX_F);
    int pack = ((int)t0 & 255) | (((int)t1 & 255) << 8) |
               (((int)t2 & 255) << 16) | ((int)t3 << 24);
    qi[j * 64 + lane] = pack;
  }
}

// ---------------------------------------------------------------------------
// Kernel 2: int8 GEMM + fused dequant — R12 (best, 16x16x64) with a 3-buffer
// SINGLE-barrier pipeline: at tile t, stage(t+2) -> buf[(t+2)%3] is issued
// right AFTER the tile-t barrier (its prior readers at tile t-1 consumed
// data into VGPRs before arriving here), so the end-of-tile barrier is
// removed (16 barrier drains vs 32) and the stage has a 2-tile latency
// window. BM=256, BN=128, BK=64, 512 thr, 8 waves (4M x 2N, wave-out 64x64).
// Tail-aware counted WAITVM(3) (R11 lesson). Phase-interleaved MFMA with
// sched_barrier + setprio. Swizzle slot^((row>>1)&3) both sides (R6:
// conflicts==0). Plain stores (R6: nt = 1.5x amplification). XCD chunk.
// LDS 72 KB; occupancy VGPR-limited at 2 blocks/CU either way.
// ---------------------------------------------------------------------------
__device__ __forceinline__ void gload_lds16(const void* g, void* l) {
  __builtin_amdgcn_global_load_lds(
      (const __attribute__((address_space(1))) void*)g,
      (__attribute__((address_space(3))) void*)l, 16, 0, 0);
}

#define BUFA_SZ 16384   // 256 rows x 64 B
#define BUFB_SZ 8192    // 128 rows x 64 B
#define BUF_SZ  (BUFA_SZ + BUFB_SZ)

// 3 gloads per thread: A 1024 chunks (2/thr), B 512 chunks (1/thr).
__device__ __forceinline__ void stage_tile(
    const signed char* __restrict__ q, const signed char* __restrict__ w,
    char* buf, int rowA0, int rowB0, int k0, int K, int tid) {
#pragma unroll
  for (int i = 0; i < 2; ++i) {
    int c  = (i << 9) + tid;
    int r  = c >> 2;
    int sl = (c & 3) ^ ((r >> 1) & 3);
    gload_lds16(q + (size_t)(rowA0 + r) * K + k0 + (sl << 4), buf + (c << 4));
  }
  {
    int c  = tid;
    int r  = c >> 2;
    int sl = (c & 3) ^ ((r >> 1) & 3);
    gload_lds16(w + (size_t)(rowB0 + r) * K + k0 + (sl << 4),
                buf + BUFA_SZ + (c << 4));
  }
}

__device__ __forceinline__ v4i lds_frag(const char* base, int row, int kb) {
  return *(const v4i*)(base + (row << 6) + ((kb ^ ((row >> 1) & 3)) << 4));
}

__global__ __launch_bounds__(512, 4) void gemm_dequant_kernel(
    const signed char* __restrict__ q, const signed char* __restrict__ w,
    const float* __restrict__ scales, const int* __restrict__ zps,
    const int* __restrict__ sums, const float* __restrict__ bias,
    const float* __restrict__ w_scales, const int* __restrict__ w_zeros,
    const int* __restrict__ w_sums, float* __restrict__ out,
    int N, int K, int nblk) {
  __shared__ char sh[3][BUF_SZ];             // 72 KB
  const int tid  = threadIdx.x;
  const int lane = tid & 63;
  const int wave = tid >> 6;                 // 0..7
  const int wrbase = (wave >> 1) << 6;       // 4 M-quarters of 64 rows
  const int wcbase = (wave & 1) << 6;        // 2 N-halves of 64 cols
  const int fr = lane & 15;
  const int kb = lane >> 4;
  const int ntN = N >> 7;                    // 8
  // XCD chunk (nblk % 8 == 0): 64 lins/XCD -> A 2 MB + w 1 MB fit 4 MB L2.
  const int per = nblk >> 3;
  const int lin = ((int)blockIdx.x & 7) * per + ((int)blockIdx.x >> 3);
  const int rowA0 = (lin / ntN) << 8;        // BM=256
  const int rowB0 = (lin % ntN) << 7;        // BN=128

  v4i acc[4][4];
#pragma unroll
  for (int i = 0; i < 4; ++i)
#pragma unroll
    for (int j = 0; j < 4; ++j) {
      v4i z = {0, 0, 0, 0};
      acc[i][j] = z;
    }

  const int NT = K >> 6;                     // 16
  stage_tile(q, w, sh[0], rowA0, rowB0, 0, K, tid);
  stage_tile(q, w, sh[1], rowA0, rowB0, 64, K, tid);

  for (int t = 0; t < NT; ++t) {
    // Tail-aware counted wait: at t=NT-1 the only outstanding loads are
    // stage(NT-1)'s own 3 -> must drain fully (R11 lesson).
    if (t + 1 < NT) { WAITVM(3); } else { WAITVM(0); }
    __builtin_amdgcn_s_barrier();            // stage(t) visible to all waves

    // Refill the buffer freed at tile t-1 (readers consumed before barrier).
    if (t + 2 < NT)
      stage_tile(q, w, sh[(t + 2) % 3], rowA0, rowB0, (t + 2) << 6, K, tid);

    const char* bA = sh[t % 3];
    const char* bB = bA + BUFA_SZ;

    // ---- phase 0: read q0 frags ----
    v4i af0 = lds_frag(bA, wrbase + 0  + fr, kb);
    v4i af1 = lds_frag(bA, wrbase + 16 + fr, kb);
    v4i bf0 = lds_frag(bB, wcbase + 0  + fr, kb);
    v4i bf1 = lds_frag(bB, wcbase + 16 + fr, kb);
    SCHEDBAR;
    // ---- phase 1: issue q1 reads, MFMA q0 ----
    v4i bf2 = lds_frag(bB, wcbase + 32 + fr, kb);
    v4i bf3 = lds_frag(bB, wcbase + 48 + fr, kb);
    __builtin_amdgcn_s_setprio(1);
    acc[0][0] = __builtin_amdgcn_mfma_i32_16x16x64_i8(af0, bf0, acc[0][0], 0, 0, 0);
    acc[0][1] = __builtin_amdgcn_mfma_i32_16x16x64_i8(af0, bf1, acc[0][1], 0, 0, 0);
    acc[1][0] = __builtin_amdgcn_mfma_i32_16x16x64_i8(af1, bf0, acc[1][0], 0, 0, 0);
    acc[1][1] = __builtin_amdgcn_mfma_i32_16x16x64_i8(af1, bf1, acc[1][1], 0, 0, 0);
    __builtin_amdgcn_s_setprio(0);
    SCHEDBAR;
    // ---- phase 2: issue q2 reads, MFMA q1 ----
    v4i af2 = lds_frag(bA, wrbase + 32 + fr, kb);
    v4i af3 = lds_frag(bA, wrbase + 48 + fr, kb);
    __builtin_amdgcn_s_setprio(1);
    acc[0][2] = __builtin_amdgcn_mfma_i32_16x16x64_i8(af0, bf2, acc[0][2], 0, 0, 0);
    acc[0][3] = __builtin_amdgcn_mfma_i32_16x16x64_i8(af0, bf3, acc[0][3], 0, 0, 0);
    acc[1][2] = __builtin_amdgcn_mfma_i32_16x16x64_i8(af1, bf2, acc[1][2], 0, 0, 0);
    acc[1][3] = __builtin_amdgcn_mfma_i32_16x16x64_i8(af1, bf3, acc[1][3], 0, 0, 0);
    __builtin_amdgcn_s_setprio(0);
    SCHEDBAR;
    // ---- phase 3: MFMA q2 + q3 ----
    __builtin_amdgcn_s_setprio(1);
    acc[2][0] = __builtin_amdgcn_mfma_i32_16x16x64_i8(af2, bf0, acc[2][0], 0, 0, 0);
    acc[2][1] = __builtin_amdgcn_mfma_i32_16x16x64_i8(af2, bf1, acc[2][1], 0, 0, 0);
    acc[3][0] = __builtin_amdgcn_mfma_i32_16x16x64_i8(af3, bf0, acc[3][0], 0, 0, 0);
    acc[3][1] = __builtin_amdgcn_mfma_i32_16x16x64_i8(af3, bf1, acc[3][1], 0, 0, 0);
    acc[2][2] = __builtin_amdgcn_mfma_i32_16x16x64_i8(af2, bf2, acc[2][2], 0, 0, 0);
    acc[2][3] = __builtin_amdgcn_mfma_i32_16x16x64_i8(af2, bf3, acc[2][3], 0, 0, 0);
    acc[3][2] = __builtin_amdgcn_mfma_i32_16x16x64_i8(af3, bf2, acc[3][2], 0, 0, 0);
    acc[3][3] = __builtin_amdgcn_mfma_i32_16x16x64_i8(af3, bf3, acc[3][3], 0, 0, 0);
    __builtin_amdgcn_s_setprio(0);
    SCHEDBAR;
  }

  // Epilogue: C/D layout col = lane&15, row = (lane>>4)*4 + reg.
  const int baseM = rowA0 + wrbase;
  const int baseN = rowB0 + wcbase;
  const int qr = (lane >> 4) << 2;
  const int qc = lane & 15;
  float cb[4], cwsc[4];
  int cwz[4], cws[4];
#pragma unroll
  for (int n = 0; n < 4; ++n) {
    int col = baseN + (n << 4) + qc;
    cb[n]   = bias[col];
    cwsc[n] = w_scales[col];
    cwz[n]  = w_zeros[col];
    cws[n]  = w_sums[col];
  }
#pragma unroll
  for (int i = 0; i < 4; ++i) {
    const int m0 = baseM + (i << 4) + qr;
    float sc[4];
    int zp4[4], sm4[4];
#pragma unroll
    for (int j = 0; j < 4; ++j) {
      sc[j]  = scales[m0 + j];
      zp4[j] = zps[m0 + j];
      sm4[j] = sums[m0 + j];
    }
#pragma unroll
    for (int n = 0; n < 4; ++n) {
      const int col = baseN + (n << 4) + qc;
#pragma unroll
      for (int j = 0; j < 4; ++j) {
        int d    = acc[i][n][j];
        int temp = zp4[j] * cws[n] + sm4[j] * cwz[n];
        out[(size_t)(m0 + j) * N + col] =
            cb[n] + (float)(d - temp) * (sc[j] * cwsc[n]);
      }
    }
  }
}

extern "C" void kernel_launch(void* const* d_in, const int* in_sizes, int n_in,
                              void* d_out, int out_size, void* d_ws, size_t ws_size,
                              hipStream_t stream) {
  const float* inp      = (const float*)d_in[0];
  const int*   qw32     = (const int*)d_in[1];   // int8 in ref -> int32 on device
  const float* bias     = (const float*)d_in[2];
  const float* w_scales = (const float*)d_in[3];
  const int*   w_zeros  = (const int*)d_in[4];
  const int*   w_sums   = (const int*)d_in[5];

  const int N = in_sizes[2];      // 1024
  const int K = in_sizes[1] / N;  // 1024
  const int M = in_sizes[0] / K;  // 16384

  float*       scales = (float*)d_ws;
  int*         zps    = (int*)((char*)d_ws + (size_t)M * 4);
  int*         sums   = (int*)((char*)d_ws + (size_t)M * 8);
  signed char* q      = (signed char*)((char*)d_ws + (size_t)M * 12);
  signed char* w8     = (signed char*)((char*)d_ws + (size_t)M * 12 + (size_t)M * K);

  const int n4 = (N * K) / 4;
  const int nblk = (M / 256) * (N / 128);    // 512 blocks = 2/CU
  quant_rows_kernel<<<M / 4, 256, 0, stream>>>(inp, q, scales, zps, sums,
                                               qw32, (int*)w8, n4, K);
  gemm_dequant_kernel<<<nblk, 512, 0, stream>>>(
      q, w8, scales, zps, sums, bias, w_scales, w_zeros, w_sums,
      (float*)d_out, N, K, nblk);
}